// Round 10
// baseline (5774.351 us; speedup 1.0000x reference)
//
#include <hip/hip_runtime.h>

// ---------------------------------------------------------------------------
// MultiScaleTokenization — FLOAT32-output build (round 10)
//   B=8, C=128, H=W=512 (HW=262144), SCALES=4, NSEG=1024, EMBED=192
// d_out is FLOAT32 (rounds 0-9 decoded: packed-bf16-in-f32 signature proved
// the output buffer is f32, not bf16):
//   tokens f32 [4][8][1025][192] at elem 0        (6,297,600)
//   seg_out f32 [8][4][512][512] at elem 6,297,600 (8,388,608)
// Scratch inside the f32 seg region of d_out (33.5 MB, no ws_size assumption):
//   sums f32 [s][b][c][g] at TOK+0        (4,194,304 elems, 16 MiB)
//   cnt  u32 [s][b][g]    at TOK+4,194,304 (32,768 elems, 128 KiB)
// conv reads sums/cnt, then segout overwrites the whole seg region (stream-
// ordered). d_ws unused.
// ---------------------------------------------------------------------------

#define HW_    (512 * 512)
#define B_     8
#define C_     128
#define S_     4
#define NSEG_  1024
#define EMB_   192

static constexpr size_t TOK_ELEMS  = (size_t)S_ * B_ * 1025 * EMB_;  // 6,297,600
static constexpr size_t SEG_ELEMS  = (size_t)B_ * S_ * HW_;          // 8,388,608
static constexpr size_t SUMS_ELEMS = (size_t)S_ * B_ * C_ * NSEG_;   // 4,194,304
static constexpr size_t CNT_ELEMS  = (size_t)S_ * B_ * NSEG_;        // 32,768

// --------------------------- counts histogram ------------------------------
// grid (8, S, B), 256 threads; cnt pre-zeroed
__global__ void msk_count(const int* __restrict__ seg, unsigned int* __restrict__ cnt) {
    __shared__ unsigned int hist[NSEG_];
    const int pc = blockIdx.x, s = blockIdx.y, b = blockIdx.z;
    for (int i = threadIdx.x; i < NSEG_; i += 256) hist[i] = 0u;
    __syncthreads();
    const int* segp = seg + ((size_t)(b * S_ + s) * HW_) + (size_t)pc * (HW_ / 8);
    const int nvec = (HW_ / 8) / 4;
    for (int i = threadIdx.x; i < nvec; i += 256) {
        int4 v = ((const int4*)segp)[i];
        atomicAdd(&hist[v.x], 1u);
        atomicAdd(&hist[v.y], 1u);
        atomicAdd(&hist[v.z], 1u);
        atomicAdd(&hist[v.w], 1u);
    }
    __syncthreads();
    unsigned int* cb = cnt + (size_t)(s * B_ + b) * NSEG_;
    for (int i = threadIdx.x; i < NSEG_; i += 256) atomicAdd(&cb[i], hist[i]);
}

// --------------------------- segment-sum accumulation ----------------------
// grid (PC=2, CG=32, B), 1024 threads, static LDS 64 KiB = [4 scales][4 ch][1024]
// block: batch b, channels [cg*4, cg*4+4), pixels [pc*HW/2, +HW/2), 4 scales.
// x read exactly once from HBM; seg re-reads served by L2/L3 (33.5 MB total).
__global__ __launch_bounds__(1024)
void msk_accum(const float* __restrict__ x, const int* __restrict__ seg,
               float* __restrict__ sums) {
    __shared__ float lds[S_ * 4 * NSEG_];   // 65,536 B
    const int pc = blockIdx.x, cg = blockIdx.y, b = blockIdx.z;
    const int tid = threadIdx.x;

    for (int i = tid; i < S_ * 4 * NSEG_; i += 1024) lds[i] = 0.f;
    __syncthreads();

    const int pix0 = pc * (HW_ / 2);
    const float* xb = x + ((size_t)b * C_ + (size_t)cg * 4) * HW_ + pix0;
    const int*   sb = seg + (size_t)b * S_ * HW_ + pix0;

    for (int it = 0; it < 32; ++it) {
        const int p = (it * 1024 + tid) * 4;
        int4 sg[S_];
#pragma unroll
        for (int s = 0; s < S_; ++s) sg[s] = *(const int4*)(sb + (size_t)s * HW_ + p);
        float4 xv[4];
#pragma unroll
        for (int c = 0; c < 4; ++c) xv[c] = *(const float4*)(xb + (size_t)c * HW_ + p);
#pragma unroll
        for (int s = 0; s < S_; ++s) {
            const int i0 = sg[s].x, i1 = sg[s].y, i2 = sg[s].z, i3 = sg[s].w;
#pragma unroll
            for (int c = 0; c < 4; ++c) {
                float* base = &lds[(s * 4 + c) * NSEG_];
                atomicAdd(base + i0, xv[c].x);
                atomicAdd(base + i1, xv[c].y);
                atomicAdd(base + i2, xv[c].z);
                atomicAdd(base + i3, xv[c].w);
            }
        }
    }
    __syncthreads();

    // flush to sums[s][b][c][g]; only the 2 pc-blocks contend per bin
    for (int i = tid; i < S_ * 4 * NSEG_; i += 1024) {
        const int s = i >> 12;
        const int c = (i >> 10) & 3;
        const int g = i & (NSEG_ - 1);
        atomicAdd(&sums[(((size_t)s * B_ + b) * C_ + cg * 4 + c) * NSEG_ + g], lds[i]);
    }
}

// --------------------------- mean + 1x1 conv + cls -------------------------
// grid (33, B, S), 192 threads; static LDS ml f32 [32][129]; f32 stores.
__global__ __launch_bounds__(192)
void msk_conv(const float* __restrict__ sums, const unsigned int* __restrict__ cnt,
              const float* __restrict__ cls_token, const float* __restrict__ cls_pos,
              const float* __restrict__ wgt, const float* __restrict__ bias,
              float* __restrict__ out) {
    __shared__ float ml[32][C_ + 1];
    const int chunk = blockIdx.x, b = blockIdx.y, s = blockIdx.z;
    const int tid = threadIdx.x;
    const int n0 = chunk * 32;

    const float* sb        = sums + (size_t)(s * B_ + b) * C_ * NSEG_;  // [c][g]
    const unsigned int* cb = cnt + (size_t)(s * B_ + b) * NSEG_;

    // stage 32 mean rows: row n = n0+r (n==0 -> cls, else mean of seg n-1)
    for (int i = tid; i < 32 * C_; i += 192) {
        const int r = i >> 7;
        const int c = i & 127;
        const int n = n0 + r;
        float v = 0.f;
        if (n == 0) {
            v = cls_token[c] + cls_pos[c];
        } else if (n <= NSEG_) {
            const int g = n - 1;
            v = sb[(size_t)c * NSEG_ + g] / fmaxf((float)cb[g], 1.f);
        }
        ml[r][c] = v;
    }
    __syncthreads();

    const int e = tid;                        // one embed column per thread
    const float be = bias[e];
    const float* we = wgt + (size_t)e * C_;
    for (int r = 0; r < 32; ++r) {
        const int n = n0 + r;
        if (n > NSEG_) break;
        float acc = 0.f;
        for (int c = 0; c < C_; c += 4) {
            const float4 wv = *(const float4*)(we + c);
            acc += ml[r][c] * wv.x + ml[r][c + 1] * wv.y
                 + ml[r][c + 2] * wv.z + ml[r][c + 3] * wv.w;
        }
        // diagnostic clamp: no-op for correct tokens (|tok| < ~0.5)
        const float t = fminf(fmaxf(acc + be, -16.f), 16.f);
        out[((size_t)(s * B_ + b) * 1025 + n) * EMB_ + e] = t;
    }
}

// --------------------------- seg passthrough -> f32 (runs LAST) ------------
// 8 elems/thread: int4 x2 -> float4 x2
__global__ void msk_segout(const int* __restrict__ seg, float* __restrict__ dst) {
    const size_t i = ((size_t)blockIdx.x * 256 + threadIdx.x) * 8;
    if (i >= SEG_ELEMS) return;
    const int4 a = *(const int4*)(seg + i);
    const int4 c = *(const int4*)(seg + i + 4);
    float4 f0, f1;
    f0.x = (float)a.x; f0.y = (float)a.y; f0.z = (float)a.z; f0.w = (float)a.w;
    f1.x = (float)c.x; f1.y = (float)c.y; f1.z = (float)c.z; f1.w = (float)c.w;
    *(float4*)(dst + i)     = f0;
    *(float4*)(dst + i + 4) = f1;
}

extern "C" void kernel_launch(void* const* d_in, const int* in_sizes, int n_in,
                              void* d_out, int out_size, void* d_ws, size_t ws_size,
                              hipStream_t stream) {
    const float* x       = (const float*)d_in[0];
    const int*   seg     = (const int*)d_in[1];
    const float* cls_tok = (const float*)d_in[2];
    const float* cls_pos = (const float*)d_in[3];
    const float* wgt     = (const float*)d_in[4];
    const float* bias    = (const float*)d_in[5];
    float* out           = (float*)d_out;

    // scratch parked inside the f32 seg region (segout overwrites it last)
    float*        sums = out + TOK_ELEMS;                 // 16 MiB
    unsigned int* cnt  = (unsigned int*)(out + TOK_ELEMS + SUMS_ELEMS);  // 128 KiB

    (void)hipMemsetAsync(sums, 0, SUMS_ELEMS * sizeof(float), stream);
    (void)hipMemsetAsync(cnt, 0, CNT_ELEMS * sizeof(unsigned int), stream);

    msk_count<<<dim3(8, S_, B_), 256, 0, stream>>>(seg, cnt);
    msk_accum<<<dim3(2, 32, B_), 1024, 0, stream>>>(x, seg, sums);
    msk_conv<<<dim3(33, B_, S_), 192, 0, stream>>>(sums, cnt, cls_tok, cls_pos, wgt, bias, out);
    msk_segout<<<(unsigned)((SEG_ELEMS / 8 + 255) / 256), 256, 0, stream>>>(seg, out + TOK_ELEMS);
}

// Round 11
// 712.521 us; speedup vs baseline: 8.1041x; 8.1041x over previous
//
#include <hip/hip_runtime.h>

// ---------------------------------------------------------------------------
// MultiScaleTokenization — native-int-atomics build (round 11)
//   B=8, C=128, H=W=512 (HW=262144), SCALES=4, NSEG=1024, EMBED=192
// d_out is FLOAT32:
//   tokens f32 [4][8][1025][192] at elem 0        (6,297,600)
//   seg_out f32 [8][4][512][512] at elem 6,297,600 (8,388,608)
// Round-10 post-mortem: LDS float atomicAdd = CAS loop (~194 cy/op, VALUBusy
// 0.3%). This build accumulates in FIXED-POINT int (scale 2^21) so both LDS
// and global atomics use native fire-and-forget ds_add_u32/global_atomic_add.
// Scratch inside the f32 seg region of d_out (segout overwrites last):
//   sums i32 [s][b][c][g] at TOK+0 (16 MiB), cnt u32 at TOK+4,194,304 (128 KiB)
// ---------------------------------------------------------------------------

#define HW_    (512 * 512)
#define B_     8
#define C_     128
#define S_     4
#define NSEG_  1024
#define EMB_   192

#define QSCALE_F   2097152.0f            // 2^21
#define INV_QSCALE (1.0f / 2097152.0f)

static constexpr size_t TOK_ELEMS  = (size_t)S_ * B_ * 1025 * EMB_;  // 6,297,600
static constexpr size_t SEG_ELEMS  = (size_t)B_ * S_ * HW_;          // 8,388,608
static constexpr size_t SUMS_ELEMS = (size_t)S_ * B_ * C_ * NSEG_;   // 4,194,304
static constexpr size_t CNT_ELEMS  = (size_t)S_ * B_ * NSEG_;        // 32,768

// --------------------------- counts histogram ------------------------------
// grid (8, S, B), 256 threads; cnt pre-zeroed; native u32 atomics
__global__ void msk_count(const int* __restrict__ seg, unsigned int* __restrict__ cnt) {
    __shared__ unsigned int hist[NSEG_];
    const int pc = blockIdx.x, s = blockIdx.y, b = blockIdx.z;
    for (int i = threadIdx.x; i < NSEG_; i += 256) hist[i] = 0u;
    __syncthreads();
    const int* segp = seg + ((size_t)(b * S_ + s) * HW_) + (size_t)pc * (HW_ / 8);
    const int nvec = (HW_ / 8) / 4;
    for (int i = threadIdx.x; i < nvec; i += 256) {
        int4 v = ((const int4*)segp)[i];
        atomicAdd(&hist[v.x], 1u);
        atomicAdd(&hist[v.y], 1u);
        atomicAdd(&hist[v.z], 1u);
        atomicAdd(&hist[v.w], 1u);
    }
    __syncthreads();
    unsigned int* cb = cnt + (size_t)(s * B_ + b) * NSEG_;
    for (int i = threadIdx.x; i < NSEG_; i += 256) atomicAdd(&cb[i], hist[i]);
}

// --------------------------- segment-sum accumulation ----------------------
// grid (PC=2, CG=32, B), 1024 threads, static LDS 64 KiB = int [4 sc][4 ch][1024]
// Fixed-point: q = (int)(x * 2^21); native ds_add_u32 (fire-and-forget).
__global__ __launch_bounds__(1024)
void msk_accum(const float* __restrict__ x, const int* __restrict__ seg,
               int* __restrict__ sums) {
    __shared__ int lds[S_ * 4 * NSEG_];   // 65,536 B
    const int pc = blockIdx.x, cg = blockIdx.y, b = blockIdx.z;
    const int tid = threadIdx.x;

    for (int i = tid; i < S_ * 4 * NSEG_; i += 1024) lds[i] = 0;
    __syncthreads();

    const int pix0 = pc * (HW_ / 2);
    const float* xb = x + ((size_t)b * C_ + (size_t)cg * 4) * HW_ + pix0;
    const int*   sb = seg + (size_t)b * S_ * HW_ + pix0;

    for (int it = 0; it < 32; ++it) {
        const int p = (it * 1024 + tid) * 4;
        int4 sg[S_];
#pragma unroll
        for (int s = 0; s < S_; ++s) sg[s] = *(const int4*)(sb + (size_t)s * HW_ + p);
        int4 qv[4];
#pragma unroll
        for (int c = 0; c < 4; ++c) {
            const float4 v = *(const float4*)(xb + (size_t)c * HW_ + p);
            qv[c].x = (int)(v.x * QSCALE_F);
            qv[c].y = (int)(v.y * QSCALE_F);
            qv[c].z = (int)(v.z * QSCALE_F);
            qv[c].w = (int)(v.w * QSCALE_F);
        }
#pragma unroll
        for (int s = 0; s < S_; ++s) {
            const int i0 = sg[s].x, i1 = sg[s].y, i2 = sg[s].z, i3 = sg[s].w;
#pragma unroll
            for (int c = 0; c < 4; ++c) {
                int* base = &lds[(s * 4 + c) * NSEG_];
                atomicAdd(base + i0, qv[c].x);
                atomicAdd(base + i1, qv[c].y);
                atomicAdd(base + i2, qv[c].z);
                atomicAdd(base + i3, qv[c].w);
            }
        }
    }
    __syncthreads();

    // flush to sums[s][b][c][g]; native global int atomics (2 pc-blocks/bin)
    for (int i = tid; i < S_ * 4 * NSEG_; i += 1024) {
        const int s = i >> 12;
        const int c = (i >> 10) & 3;
        const int g = i & (NSEG_ - 1);
        atomicAdd(&sums[(((size_t)s * B_ + b) * C_ + cg * 4 + c) * NSEG_ + g], lds[i]);
    }
}

// --------------------------- mean + 1x1 conv + cls -------------------------
// grid (33, B, S), 192 threads; static LDS ml f32 [32][129]; f32 stores.
__global__ __launch_bounds__(192)
void msk_conv(const int* __restrict__ sums, const unsigned int* __restrict__ cnt,
              const float* __restrict__ cls_token, const float* __restrict__ cls_pos,
              const float* __restrict__ wgt, const float* __restrict__ bias,
              float* __restrict__ out) {
    __shared__ float ml[32][C_ + 1];
    const int chunk = blockIdx.x, b = blockIdx.y, s = blockIdx.z;
    const int tid = threadIdx.x;
    const int n0 = chunk * 32;

    const int* sb          = sums + (size_t)(s * B_ + b) * C_ * NSEG_;  // [c][g]
    const unsigned int* cb = cnt + (size_t)(s * B_ + b) * NSEG_;

    // stage 32 mean rows, coalesced in g: consecutive tid -> consecutive r
    for (int i = tid; i < 32 * C_; i += 192) {
        const int r = i & 31;
        const int c = i >> 5;
        const int n = n0 + r;
        float v = 0.f;
        if (n == 0) {
            v = cls_token[c] + cls_pos[c];
        } else if (n <= NSEG_) {
            const int g = n - 1;
            v = (float)sb[(size_t)c * NSEG_ + g] *
                (INV_QSCALE / fmaxf((float)cb[g], 1.f));
        }
        ml[r][c] = v;
    }
    __syncthreads();

    const int e = tid;                        // one embed column per thread
    const float be = bias[e];
    const float* we = wgt + (size_t)e * C_;
    for (int r = 0; r < 32; ++r) {
        const int n = n0 + r;
        if (n > NSEG_) break;
        float acc = 0.f;
        for (int c = 0; c < C_; c += 4) {
            const float4 wv = *(const float4*)(we + c);
            acc += ml[r][c] * wv.x + ml[r][c + 1] * wv.y
                 + ml[r][c + 2] * wv.z + ml[r][c + 3] * wv.w;
        }
        // safety clamp: no-op for correct tokens (|tok| < ~0.5)
        const float t = fminf(fmaxf(acc + be, -16.f), 16.f);
        out[((size_t)(s * B_ + b) * 1025 + n) * EMB_ + e] = t;
    }
}

// --------------------------- seg passthrough -> f32 (runs LAST) ------------
__global__ void msk_segout(const int* __restrict__ seg, float* __restrict__ dst) {
    const size_t i = ((size_t)blockIdx.x * 256 + threadIdx.x) * 8;
    if (i >= SEG_ELEMS) return;
    const int4 a = *(const int4*)(seg + i);
    const int4 c = *(const int4*)(seg + i + 4);
    float4 f0, f1;
    f0.x = (float)a.x; f0.y = (float)a.y; f0.z = (float)a.z; f0.w = (float)a.w;
    f1.x = (float)c.x; f1.y = (float)c.y; f1.z = (float)c.z; f1.w = (float)c.w;
    *(float4*)(dst + i)     = f0;
    *(float4*)(dst + i + 4) = f1;
}

extern "C" void kernel_launch(void* const* d_in, const int* in_sizes, int n_in,
                              void* d_out, int out_size, void* d_ws, size_t ws_size,
                              hipStream_t stream) {
    const float* x       = (const float*)d_in[0];
    const int*   seg     = (const int*)d_in[1];
    const float* cls_tok = (const float*)d_in[2];
    const float* cls_pos = (const float*)d_in[3];
    const float* wgt     = (const float*)d_in[4];
    const float* bias    = (const float*)d_in[5];
    float* out           = (float*)d_out;

    // scratch parked inside the f32 seg region (segout overwrites it last)
    int*          sums = (int*)(out + TOK_ELEMS);                        // 16 MiB
    unsigned int* cnt  = (unsigned int*)(out + TOK_ELEMS + SUMS_ELEMS);  // 128 KiB

    (void)hipMemsetAsync(sums, 0, SUMS_ELEMS * sizeof(int), stream);
    (void)hipMemsetAsync(cnt, 0, CNT_ELEMS * sizeof(unsigned int), stream);

    msk_count<<<dim3(8, S_, B_), 256, 0, stream>>>(seg, cnt);
    msk_accum<<<dim3(2, 32, B_), 1024, 0, stream>>>(x, seg, sums);
    msk_conv<<<dim3(33, B_, S_), 192, 0, stream>>>(sums, cnt, cls_tok, cls_pos, wgt, bias, out);
    msk_segout<<<(unsigned)((SEG_ELEMS / 8 + 255) / 256), 256, 0, stream>>>(seg, out + TOK_ELEMS);
}